// Round 21
// baseline (204.152 us; speedup 1.0000x reference)
//
#include <hip/hip_runtime.h>
#include <hip/hip_bf16.h>
#include <cstdint>
#include <math.h>

// Problem constants
#define DM   1024
#define NH   16
#define DH   64
#define BB   4
#define TT   2048
#define MTOT (BB*TT)   // 8192 rows

using short8 = __attribute__((ext_vector_type(8))) short;  // 8 bf16 (4 VGPRs)
using f32x4  = __attribute__((ext_vector_type(4))) float;

__device__ __forceinline__ f32x4 mfma16(short8 a, short8 b, f32x4 c) {
  return __builtin_amdgcn_mfma_f32_16x16x32_bf16(a, b, c, 0, 0, 0);
}

typedef const __attribute__((address_space(1))) unsigned int* as1_u32p;
typedef __attribute__((address_space(3))) unsigned int*       as3_u32p;

// async global->LDS, 16B per lane; LDS dest = wave-uniform base + lane*16 (linear)
__device__ __forceinline__ void gl_lds16(const void* g, void* l) {
  __builtin_amdgcn_global_load_lds(
      (as1_u32p)(reinterpret_cast<uintptr_t>(g)),
      (as3_u32p)((unsigned int)(reinterpret_cast<uintptr_t>(l))),
      16, 0, 0);
}

// XOR swizzle for tiles with 64-elem (128B) rows: 8 slots of 8 bf16; slot ^= row&7
__device__ __forceinline__ int swz64(int row, int col) {
  return row*64 + ((((col >> 3) ^ (row & 7)) << 3) | (col & 7));
}

__device__ __forceinline__ unsigned pkbf(float a, float b) {
  __hip_bfloat162 h = __float22bfloat162_rn(make_float2(a, b)); // x=lo, y=hi
  return *reinterpret_cast<unsigned*>(&h);
}

// permlane swaps (VALU pipe). Verified row semantics (involutions):
// perm16(d,s): d'=[d0,s0,d2,s2], s'=[d1,s1,d3,s3]   (16-lane rows)
// perm32(d,s): d'=[d0,d1,s0,s1], s'=[d2,d3,s2,s3]
__device__ __forceinline__ void perm16p(unsigned &a, unsigned &b) {
  asm("v_permlane16_swap_b32 %0, %1" : "+v"(a), "+v"(b));
}
__device__ __forceinline__ void perm32p(unsigned &a, unsigned &b) {
  asm("v_permlane32_swap_b32 %0, %1" : "+v"(a), "+v"(b));
}

// inline-asm LDS reads (opaque to alias analysis: no compiler-inserted vmcnt drains)
__device__ __forceinline__ short8 ldsr_o0(unsigned a) {
  short8 r; asm volatile("ds_read_b128 %0, %1" : "=v"(r) : "v"(a)); return r;
}
__device__ __forceinline__ short8 ldsr_o1(unsigned a) {
  short8 r; asm volatile("ds_read_b128 %0, %1 offset:2048" : "=v"(r) : "v"(a)); return r;
}
__device__ __forceinline__ short8 ldsr_o2(unsigned a) {
  short8 r; asm volatile("ds_read_b128 %0, %1 offset:4096" : "=v"(r) : "v"(a)); return r;
}
__device__ __forceinline__ short8 ldsr_o3(unsigned a) {
  short8 r; asm volatile("ds_read_b128 %0, %1 offset:6144" : "=v"(r) : "v"(a)); return r;
}
__device__ __forceinline__ short8 ldsr_o4(unsigned a) {
  short8 r; asm volatile("ds_read_b128 %0, %1 offset:8192" : "=v"(r) : "v"(a)); return r;
}
__device__ __forceinline__ short8 ldsr_o5(unsigned a) {
  short8 r; asm volatile("ds_read_b128 %0, %1 offset:10240" : "=v"(r) : "v"(a)); return r;
}

#define LGKM0  do { asm volatile("s_waitcnt lgkmcnt(0)"); __builtin_amdgcn_sched_barrier(0); } while(0)
#define VMCNT0 do { __builtin_amdgcn_sched_barrier(0); asm volatile("s_waitcnt vmcnt(0)"); __builtin_amdgcn_sched_barrier(0); } while(0)
#define BARRIER do { __builtin_amdgcn_s_barrier(); __builtin_amdgcn_sched_barrier(0); } while(0)

// ---------------- fp32 -> bf16 copy convert ----------------
__global__ __launch_bounds__(256) void k_cvt(const float* __restrict__ in,
                                             __hip_bfloat16* __restrict__ out, int n8) {
  int i = blockIdx.x * 256 + threadIdx.x;
  if (i >= n8) return;
  const float* p = in + (size_t)i * 8;
  short8 o;
#pragma unroll
  for (int j = 0; j < 8; ++j) {
    __hip_bfloat16 h = __float2bfloat16(p[j]);
    o[j] = *reinterpret_cast<short*>(&h);
  }
  *reinterpret_cast<short8*>(out + (size_t)i * 8) = o;
}

// ---------------- W [K][N] fp32 -> Wt [N][K] bf16 (tiled transpose) ----------------
__global__ __launch_bounds__(256) void k_transpose_cvt(const float* __restrict__ W,
                                                       __hip_bfloat16* __restrict__ Wt,
                                                       int K, int N) {
  __shared__ float tbuf[32][33];
  const int n0 = blockIdx.x * 32, k0 = blockIdx.y * 32;
  const int tx = threadIdx.x & 31, ty = threadIdx.x >> 5;
#pragma unroll
  for (int i = 0; i < 4; ++i)
    tbuf[ty + i*8][tx] = W[(size_t)(k0 + ty + i*8) * N + n0 + tx];
  __syncthreads();
#pragma unroll
  for (int i = 0; i < 4; ++i)
    Wt[(size_t)(n0 + ty + i*8) * K + k0 + tx] = __float2bfloat16(tbuf[tx][ty + i*8]);
}

// ---------------- 128x192 double-buffered QKV GEMM, 2 blocks/CU (r16-proven) ----------------
__global__ __launch_bounds__(512, 4) void k_gemm3(const __hip_bfloat16* __restrict__ A,
                                                  const __hip_bfloat16* __restrict__ Bt,
                                                  const float* __restrict__ bias,
                                                  __hip_bfloat16* __restrict__ Qb,
                                                  __hip_bfloat16* __restrict__ Kb,
                                                  __hip_bfloat16* __restrict__ Vtb) {
  __shared__ __hip_bfloat16 As[2][128 * 64];   // 16 KB per slot
  __shared__ __hip_bfloat16 Bs[2][192 * 64];   // 24 KB per slot
  const int tid = threadIdx.x;
  const int l = tid & 63, w = tid >> 6;
  const int lr = l & 15, lg = l >> 4;
  const int wm = w >> 2, wn = w & 3;           // 2m x 4n: 64 rows x 48 cols per wave
  const int m0 = blockIdx.x * 128, n0 = blockIdx.y * 192;

  const int srow = tid >> 3;                   // 0..63
  const int scol = (((tid & 7) ^ (srow & 7)) << 3);
  const size_t aoffs = (size_t)(m0 + srow) * 1024 + scol;
  const size_t boffs = (size_t)(n0 + srow) * 1024 + scol;
  const int ldst = tid * 8;

  auto stage = [&](int t, int s) {
    const int k0 = t * 64;
#pragma unroll
    for (int rd = 0; rd < 2; ++rd)
      gl_lds16(A + aoffs + (size_t)rd * 65536 + k0, &As[s][rd * 4096 + ldst]);
#pragma unroll
    for (int rd = 0; rd < 3; ++rd)
      gl_lds16(Bt + boffs + (size_t)rd * 65536 + k0, &Bs[s][rd * 4096 + ldst]);
  };

  const unsigned asLds = (unsigned)(uintptr_t)&As[0][0];
  const unsigned bsLds = (unsigned)(uintptr_t)&Bs[0][0];
  const unsigned aBase0 = asLds + 2u * ((wm*64 + lr) * 64 + ((lg ^ (lr & 7)) << 3));
  const unsigned bBase0 = bsLds + 2u * ((wn*48 + lr) * 64 + ((lg ^ (lr & 7)) << 3));

  stage(0, 0);
  VMCNT0;
  BARRIER;

  f32x4 acc[4][3] = {};
  short8 a_[4][2], b_[3][2];

#pragma unroll
  for (int t = 0; t < 16; ++t) {
    const int s = t & 1;
    const unsigned aB0 = aBase0 + (unsigned)s * 16384u;
    const unsigned aB1 = aB0 ^ 64u;
    const unsigned bB0 = bBase0 + (unsigned)s * 24576u;
    const unsigned bB1 = bB0 ^ 64u;
    if (t < 15) stage(t + 1, s ^ 1);
    a_[0][0] = ldsr_o0(aB0); a_[1][0] = ldsr_o1(aB0); a_[2][0] = ldsr_o2(aB0); a_[3][0] = ldsr_o3(aB0);
    a_[0][1] = ldsr_o0(aB1); a_[1][1] = ldsr_o1(aB1); a_[2][1] = ldsr_o2(aB1); a_[3][1] = ldsr_o3(aB1);
    b_[0][0] = ldsr_o0(bB0); b_[1][0] = ldsr_o1(bB0); b_[2][0] = ldsr_o2(bB0);
    b_[0][1] = ldsr_o0(bB1); b_[1][1] = ldsr_o1(bB1); b_[2][1] = ldsr_o2(bB1);
    LGKM0;
    __builtin_amdgcn_s_setprio(1);
#pragma unroll
    for (int m = 0; m < 4; ++m)
#pragma unroll
      for (int n = 0; n < 3; ++n)
#pragma unroll
        for (int ks = 0; ks < 2; ++ks)
          acc[m][n] = mfma16(a_[m][ks], b_[n][ks], acc[m][n]);
    __builtin_amdgcn_s_setprio(0);
    if (t < 15) { VMCNT0; }
    BARRIER;
  }

  __syncthreads();
  // ---- per-16-col-group LDS-bounce epilogue (3 groups/wave) ----
  __hip_bfloat16* reg = &Bs[0][0] + w * 3072;   // 8 waves x 3 groups x 1024 elems
  const int colbase = n0 + wn * 48;
  const int rowbase = m0 + wm * 64;
  const int bidx = rowbase >> 11;
  const int tbase = rowbase & 2047;
  const float qs = 0.18033688011112042f;   // 0.125 * log2(e) folded into Q
  float bv[3];
#pragma unroll
  for (int g = 0; g < 3; ++g) bv[g] = bias[colbase + g * 16 + lr];
#pragma unroll
  for (int g = 0; g < 3; ++g) {
    const int cg0 = colbase + g * 16;
    const int which = cg0 >> 10;
    __hip_bfloat16* rg = reg + g * 1024;
    if (which == 2) {
#pragma unroll
      for (int m = 0; m < 4; ++m)
#pragma unroll
        for (int r = 0; r < 4; ++r) {
          const int t = m * 16 + lg * 4 + r;
          rg[lr * 64 + (t ^ ((lr & 7) << 3))] = __float2bfloat16(acc[m][g][r] + bv[g]);
        }
    } else {
      const float sc = (which == 0) ? qs : 1.f;
#pragma unroll
      for (int m = 0; m < 4; ++m)
#pragma unroll
        for (int r = 0; r < 4; ++r) {
          const int t = m * 16 + lg * 4 + r;
          rg[t * 16 + (lr ^ (((t >> 2) & 1) << 3))] =
              __float2bfloat16((acc[m][g][r] + bv[g]) * sc);
        }
    }
  }
#pragma unroll
  for (int g = 0; g < 3; ++g) {
    const int cg0 = colbase + g * 16;
    const int which = cg0 >> 10;
    const int hh = (cg0 >> 6) & 15;
    const int dd0 = cg0 & 48;
    const size_t bh = (size_t)bidx * 16 + hh;
    const __hip_bfloat16* rg = reg + g * 1024;
    if (which < 2) {
      __hip_bfloat16* basep = (which == 0) ? Qb : Kb;
      const int t = l;
      const int Xc = ((t >> 2) & 1) << 3;
      short8 y0 = *reinterpret_cast<const short8*>(&rg[t * 16 + Xc]);
      short8 y1 = *reinterpret_cast<const short8*>(&rg[t * 16 + (Xc ^ 8)]);
      __hip_bfloat16* dst = basep + (bh * TT + tbase + t) * 64 + dd0;
      *reinterpret_cast<short8*>(dst) = y0;
      *reinterpret_cast<short8*>(dst + 8) = y1;
    } else {
      const int dd = l >> 2, tseg = l & 3;
      const int X = (dd & 7) << 3;
      const int S0 = (((tseg ^ (X >> 4)) & 3) << 4) | (X & 8);
      short8 y0 = *reinterpret_cast<const short8*>(&rg[dd * 64 + S0]);
      short8 y1 = *reinterpret_cast<const short8*>(&rg[dd * 64 + (S0 ^ 8)]);
      __hip_bfloat16* dst = Vtb + (bh * 64 + dd0 + dd) * TT + tbase + tseg * 16;
      *reinterpret_cast<short8*>(dst) = y0;
      *reinterpret_cast<short8*>(dst + 8) = y1;
    }
  }
}

// ---------------- 128x128 double-buffered dist-1 GEMM (proj), 2 blocks/CU ----------------
__global__ __launch_bounds__(256, 2) void k_gemm2(const __hip_bfloat16* __restrict__ A,
                                                  const __hip_bfloat16* __restrict__ Bt,
                                                  const float* __restrict__ bias,
                                                  float* __restrict__ outF) {
  __shared__ __hip_bfloat16 As[2][128 * 64];
  __shared__ __hip_bfloat16 Bs[2][128 * 64];
  const int tid = threadIdx.x;
  const int l = tid & 63, w = tid >> 6;
  const int lr = l & 15, lg = l >> 4;
  const int wm = w >> 1, wn = w & 1;
  const int m0 = blockIdx.x * 128, n0 = blockIdx.y * 128;

  const int srow = tid >> 3;                 // 0..31
  const int scol = (((tid & 7) ^ (srow & 7)) << 3);
  const size_t aoffs = (size_t)(m0 + srow) * 1024 + scol;
  const size_t boffs = (size_t)(n0 + srow) * 1024 + scol;
  const int ldst = tid * 8;

  auto stage = [&](int t, int s) {
    const int k0 = t * 64;
#pragma unroll
    for (int rd = 0; rd < 4; ++rd) {
      gl_lds16(A + aoffs + (size_t)rd * 32768 + k0, &As[s][rd * 2048 + ldst]);
      gl_lds16(Bt + boffs + (size_t)rd * 32768 + k0, &Bs[s][rd * 2048 + ldst]);
    }
  };

  const unsigned asLds = (unsigned)(uintptr_t)&As[0][0];
  const unsigned bsLds = (unsigned)(uintptr_t)&Bs[0][0];
  const unsigned aBase0 = asLds + 2u * ((wm*64 + lr) * 64 + ((lg ^ (lr & 7)) << 3));
  const unsigned bBase0 = bsLds + 2u * ((wn*64 + lr) * 64 + ((lg ^ (lr & 7)) << 3));

  stage(0, 0);
  VMCNT0;
  BARRIER;

  f32x4 acc[4][4] = {};
  short8 a_[4][2], b_[4][2];

#pragma unroll
  for (int t = 0; t < 16; ++t) {
    const int s = t & 1;
    const unsigned aB0 = aBase0 + (unsigned)s * 16384u;
    const unsigned aB1 = aB0 ^ 64u;
    const unsigned bB0 = bBase0 + (unsigned)s * 16384u;
    const unsigned bB1 = bB0 ^ 64u;
    if (t < 15) stage(t + 1, s ^ 1);
    a_[0][0] = ldsr_o0(aB0); a_[1][0] = ldsr_o1(aB0); a_[2][0] = ldsr_o2(aB0); a_[3][0] = ldsr_o3(aB0);
    a_[0][1] = ldsr_o0(aB1); a_[1][1] = ldsr_o1(aB1); a_[2][1] = ldsr_o2(aB1); a_[3][1] = ldsr_o3(aB1);
    b_[0][0] = ldsr_o0(bB0); b_[1][0] = ldsr_o1(bB0); b_[2][0] = ldsr_o2(bB0); b_[3][0] = ldsr_o3(bB0);
    b_[0][1] = ldsr_o0(bB1); b_[1][1] = ldsr_o1(bB1); b_[2][1] = ldsr_o2(bB1); b_[3][1] = ldsr_o3(bB1);
    LGKM0;
    __builtin_amdgcn_s_setprio(1);
#pragma unroll
    for (int m = 0; m < 4; ++m)
#pragma unroll
      for (int n = 0; n < 4; ++n)
#pragma unroll
        for (int ks = 0; ks < 2; ++ks)
          acc[m][n] = mfma16(a_[m][ks], b_[n][ks], acc[m][n]);
    __builtin_amdgcn_s_setprio(0);
    if (t < 15) { VMCNT0; }
    BARRIER;
  }

  __syncthreads();
#pragma unroll
  for (int n = 0; n < 4; ++n) {
    const int col = n0 + wn * 64 + n * 16 + lr;
    const float bvv = bias[col];
#pragma unroll
    for (int m = 0; m < 4; ++m)
#pragma unroll
      for (int r = 0; r < 4; ++r) {
        const int row = m0 + wm * 64 + m * 16 + lg * 4 + r;
        outF[(size_t)row * 1024 + col] = acc[m][n][r] + bvv;
      }
  }
}

// ---------------- causal flash attention (merged pairs, mfma-lrun, T14 compiler-tracked) ----------------
// Fixed-max softmax, sigma-permuted K rows, permlane P-redistribution, mfma row-sum.
// T14 staging uses PLAIN C++ loads/stores (compiler-tracked): kreg loaded right after the
// top barrier (latency hides under compute; bottom __syncthreads drains vmcnt exactly
// there), stored to LDS after the bottom barrier (lgkm drained by next top barrier).
// No inline asm in the staging path -> no untracked-register hazards.
__device__ __forceinline__ void tile_step(f32x4 s0, f32x4 s1, int kbase, int kmaxw, int qmb,
                                          short8 ones,
                                          short8 v0, short8 v1, short8 v2, short8 v3,
                                          f32x4 (&acc)[4], f32x4& accL) {
  if (kbase + 31 > kmaxw - 15) {       // diagonal chunk: per-element causal mask
#pragma unroll
    for (int r = 0; r < 4; ++r) {
      const int off = (r & 1) + ((r & 2) << 2);   // 0,1,8,9
      if (kbase + off > qmb)      s0[r] = -INFINITY;
      if (kbase + 16 + off > qmb) s1[r] = -INFINITY;
    }
  }
  float p0 = __builtin_amdgcn_exp2f(s0[0]), p1 = __builtin_amdgcn_exp2f(s0[1]);
  float p2 = __builtin_amdgcn_exp2f(s0[2]), p3 = __builtin_amdgcn_exp2f(s0[3]);
  float p4 = __builtin_amdgcn_exp2f(s1[0]), p5 = __builtin_amdgcn_exp2f(s1[1]);
  float p6 = __builtin_amdgcn_exp2f(s1[2]), p7 = __builtin_amdgcn_exp2f(s1[3]);
  unsigned u0 = pkbf(p0, p1);
  unsigned u1 = pkbf(p2, p3);
  unsigned u2 = pkbf(p4, p5);
  unsigned u3 = pkbf(p6, p7);
  perm16p(u0, u1);
  perm16p(u2, u3);
  perm32p(u0, u2);
  perm32p(u1, u3);
  union { unsigned u[4]; short8 s; } pw;
  pw.u[0] = u0; pw.u[1] = u2; pw.u[2] = u1; pw.u[3] = u3;
  const short8 pf = pw.s;
  acc[0] = mfma16(v0, pf, acc[0]);
  acc[1] = mfma16(v1, pf, acc[1]);
  acc[2] = mfma16(v2, pf, acc[2]);
  acc[3] = mfma16(v3, pf, acc[3]);
  accL   = mfma16(ones, pf, accL);   // row-sum of P on the MFMA pipe
}

__device__ __forceinline__ void store_tile(__hip_bfloat16* Ylds, f32x4 (&acc)[4],
                                           float lsum, int q0, int w, int l,
                                           int lr, int lg, int bh,
                                           __hip_bfloat16* __restrict__ Y) {
  const float inv = 1.f / lsum;
#pragma unroll
  for (int nb = 0; nb < 4; ++nb) {
#pragma unroll
    for (int r = 0; r < 4; ++r) {
      const int d = nb * 16 + lg * 4 + r;
      Ylds[swz64(lr, d)] = __float2bfloat16(acc[nb][r] * inv);
    }
  }
  const int rr = l >> 2, part = l & 3;
  const int trow = q0 + w * 16 + rr;
  const int b = bh >> 4, h = bh & 15;
  short8 y0 = *reinterpret_cast<const short8*>(&Ylds[swz64(rr, part * 16)]);
  short8 y1 = *reinterpret_cast<const short8*>(&Ylds[swz64(rr, part * 16 + 8)]);
  __hip_bfloat16* dst = Y + ((size_t)b * TT + trow) * 1024 + h * 64 + part * 16;
  *reinterpret_cast<short8*>(dst) = y0;
  *reinterpret_cast<short8*>(dst + 8) = y1;
}

__global__ __launch_bounds__(256, 4) void k_flash(const __hip_bfloat16* __restrict__ Qb,
                                                  const __hip_bfloat16* __restrict__ Kb,
                                                  const __hip_bfloat16* __restrict__ Vtb,
                                                  __hip_bfloat16* __restrict__ Y) {
  __shared__ __hip_bfloat16 Klds[128 * 64];
  __shared__ __hip_bfloat16 Vtlds[64 * 128];
  const int tid = threadIdx.x;
  const int l = tid & 63, w = tid >> 6;
  const int lr = l & 15, lg = l >> 4;
  const int p  = blockIdx.x >> 6;       // pair index 0..15
  const int bh = blockIdx.x & 63;
  const int q0A = p * 64, q0B = (31 - p) * 64;
  const __hip_bfloat16* Qp = Qb + (size_t)bh * TT * 64;
  const __hip_bfloat16* Kp = Kb + (size_t)bh * TT * 64;
  const __hip_bfloat16* Vp = Vtb + (size_t)bh * 64 * TT;
  const int qrowA = q0A + w * 16 + lr;
  const int qrowB = q0B + w * 16 + lr;
  const short8 qfA0 = *reinterpret_cast<const short8*>(Qp + (size_t)qrowA * 64 + lg * 8);
  const short8 qfA1 = *reinterpret_cast<const short8*>(Qp + (size_t)qrowA * 64 + 32 + lg * 8);
  const short8 qfB0 = *reinterpret_cast<const short8*>(Qp + (size_t)qrowB * 64 + lg * 8);
  const short8 qfB1 = *reinterpret_cast<const short8*>(Qp + (size_t)qrowB * 64 + 32 + lg * 8);
  f32x4 accA[4] = {}, accB[4] = {};
  f32x4 accLA = {}, accLB = {};
  union { unsigned u[4]; short8 s; } onesu;
  onesu.u[0] = onesu.u[1] = onesu.u[2] = onesu.u[3] = 0x3F803F80u;  // bf16 1.0 pairs
  const short8 ones = onesu.s;

  const int ka  = lr * 64 + ((lg ^ (lr & 7)) << 3);
  const int va  = lr * 128 + ((lg ^ (lr & 15)) << 3);

  const __hip_bfloat16* gk[4];
  const __hip_bfloat16* gv[4];
  __hip_bfloat16* lkp[4];
  __hip_bfloat16* lvp[4];
#pragma unroll
  for (int it = 0; it < 4; ++it) {
    int e = it * 2048 + tid * 8;
    int rowk = e >> 6;
    int lcolk = ((((e >> 3) & 7) ^ (rowk & 7)) << 3);
    int rk = rowk & 15;
    int srk = (((rk >> 1) ^ (rk >> 3)) & 1) ? (rk ^ 10) : rk;
    int rowks = (rowk & ~15) | srk;
    gk[it] = Kp + (size_t)rowks * 64 + lcolk;
    lkp[it] = &Klds[e];
    int rowv = e >> 7;
    int lcolv = ((((e >> 3) & 15) ^ (rowv & 15)) << 3);
    gv[it] = Vp + (size_t)rowv * TT + lcolv;
    lvp[it] = &Vtlds[e];
  }

  const int kmaxwA = q0A + w * 16 + 15;
  const int kmaxwB = q0B + w * 16 + 15;
  const int base_lg = ((lg & 1) << 2) | (lg & 2);
  const int qmbA = qrowA - base_lg;
  const int qmbB = qrowB - base_lg;
  const int nblk = (q0B + 63) / 128 + 1;

  // prologue: stage block 0 via DMA (tracked builtin; first barrier drains it)
#pragma unroll
  for (int it = 0; it < 4; ++it) {
    gl_lds16(gk[it], lkp[it]);
    gk[it] += 8192;
  }
#pragma unroll
  for (int it = 0; it < 4; ++it) {
    gl_lds16(gv[it], lvp[it]);
    gv[it] += 128;
  }

  short8 kreg[4], vreg[4];
  for (int blk = 0; blk < nblk; ++blk) {
    const int kv0 = blk * 128;
    __syncthreads();                     // block data ready (DMA or published stores)
    const bool pf = (blk + 1 < nblk);
    if (pf) {                            // issue next block's loads (compiler-tracked)
#pragma unroll
      for (int it = 0; it < 4; ++it) {
        kreg[it] = *reinterpret_cast<const short8*>(gk[it]);
        gk[it] += 8192;
      }
#pragma unroll
      for (int it = 0; it < 4; ++it) {
        vreg[it] = *reinterpret_cast<const short8*>(gv[it]);
        gv[it] += 128;
      }
      __builtin_amdgcn_sched_barrier(0); // pin issue point before compute
    }
#pragma unroll
    for (int kci = 0; kci < 4; ++kci) {
      const int kbase = kv0 + kci * 32;
      if (kbase > kmaxwB) break;
      const int kb = ka + kci * 2048;
      const short8 kf00 = *reinterpret_cast<const short8*>(&Klds[kb]);
      const short8 kf10 = *reinterpret_cast<const short8*>(&Klds[kb + 1024]);
      const short8 kf01 = *reinterpret_cast<const short8*>(&Klds[kb ^ 32]);
      const short8 kf11 = *reinterpret_cast<const short8*>(&Klds[(kb + 1024) ^ 32]);
      f32x4 sB0 = {}, sB1 = {};
      sB0 = mfma16(kf00, qfB0, sB0);
      sB1 = mfma16(kf10, qfB0, sB1);
      sB0 = mfma16(kf01, qfB1, sB0);
      sB1 = mfma16(kf11, qfB1, sB1);
      const bool aAct = (kbase <= kmaxwA);
      f32x4 sA0 = {}, sA1 = {};
      if (aAct) {
        sA0 = mfma16(kf00, qfA0, sA0);
        sA1 = mfma16(kf10, qfA0, sA1);
        sA0 = mfma16(kf01, qfA1, sA0);
        sA1 = mfma16(kf11, qfA1, sA1);
      }
      const int vb = va ^ (kci * 32);
      const short8 v0 = *reinterpret_cast<const short8*>(&Vtlds[vb]);
      const short8 v1 = *reinterpret_cast<const short8*>(&Vtlds[vb + 2048]);
      const short8 v2 = *reinterpret_cast<const short8*>(&Vtlds[vb + 4096]);
      const short8 v3 = *reinterpret_cast<const short8*>(&Vtlds[vb + 6144]);
      tile_step(sB0, sB1, kbase, kmaxwB, qmbB, ones, v0, v1, v2, v3, accB, accLB);
      if (aAct)
        tile_step(sA0, sA1, kbase, kmaxwA, qmbA, ones, v0, v1, v2, v3, accA, accLA);
    }
    __syncthreads();                     // all waves done reading this block's LDS
    if (pf) {                            // store staged regs (compiler-tracked ds_write)
#pragma unroll
      for (int it = 0; it < 4; ++it)
        *reinterpret_cast<short8*>(lkp[it]) = kreg[it];
#pragma unroll
      for (int it = 0; it < 4; ++it)
        *reinterpret_cast<short8*>(lvp[it]) = vreg[it];
    }
  }
  __hip_bfloat16* Ylds = Klds + w * 1024;
  store_tile(Ylds, accA, accLA[0], q0A, w, l, lr, lg, bh, Y);
  store_tile(Ylds, accB, accLB[0], q0B, w, l, lr, lg, bh, Y);
}

// ---------------- launch ----------------
extern "C" void kernel_launch(void* const* d_in, const int* in_sizes, int n_in,
                              void* d_out, int out_size, void* d_ws, size_t ws_size,
                              hipStream_t stream) {
  const float* x     = (const float*)d_in[0];
  const float* Wqkv  = (const float*)d_in[1];
  const float* bqkv  = (const float*)d_in[2];
  const float* Wproj = (const float*)d_in[3];
  const float* bproj = (const float*)d_in[4];

  char* ws = (char*)d_ws;
  size_t off = 0;
  auto alloc = [&](size_t bytes) {
    char* p = ws + off;
    off += (bytes + 255) & ~(size_t)255;
    return p;
  };
  __hip_bfloat16* xb    = (__hip_bfloat16*)alloc((size_t)MTOT * 1024 * 2);
  __hip_bfloat16* wqkvT = (__hip_bfloat16*)alloc((size_t)3072 * 1024 * 2);
  __hip_bfloat16* wpT   = (__hip_bfloat16*)alloc((size_t)1024 * 1024 * 2);
  __hip_bfloat16* Qb    = (__hip_bfloat16*)alloc((size_t)64 * TT * 64 * 2);
  __hip_bfloat16* Kb    = (__hip_bfloat16*)alloc((size_t)64 * TT * 64 * 2);
  __hip_bfloat16* Vtb   = (__hip_bfloat16*)alloc((size_t)64 * TT * 64 * 2);
  __hip_bfloat16* Yb    = (__hip_bfloat16*)alloc((size_t)MTOT * 1024 * 2);

  k_cvt<<<(MTOT * 1024 / 8 + 255) / 256, 256, 0, stream>>>(x, xb, MTOT * 1024 / 8);
  k_transpose_cvt<<<dim3(3072 / 32, 1024 / 32), 256, 0, stream>>>(Wqkv, wqkvT, 1024, 3072);
  k_transpose_cvt<<<dim3(1024 / 32, 1024 / 32), 256, 0, stream>>>(Wproj, wpT, 1024, 1024);
  k_gemm3<<<dim3(64, 16), 512, 0, stream>>>(xb, wqkvT, bqkv, Qb, Kb, Vtb);
  k_flash<<<16 * 64, 256, 0, stream>>>(Qb, Kb, Vtb, Yb);
  k_gemm2<<<dim3(64, 8), 256, 0, stream>>>(Yb, wpT, bproj, (float*)d_out);
}

// Round 22
// 139.375 us; speedup vs baseline: 1.4648x; 1.4648x over previous
//
#include <hip/hip_runtime.h>
#include <hip/hip_bf16.h>
#include <cstdint>
#include <math.h>

// Problem constants
#define DM   1024
#define NH   16
#define DH   64
#define BB   4
#define TT   2048
#define MTOT (BB*TT)   // 8192 rows

using short8 = __attribute__((ext_vector_type(8))) short;  // 8 bf16 (4 VGPRs)
using f32x4  = __attribute__((ext_vector_type(4))) float;

__device__ __forceinline__ f32x4 mfma16(short8 a, short8 b, f32x4 c) {
  return __builtin_amdgcn_mfma_f32_16x16x32_bf16(a, b, c, 0, 0, 0);
}

typedef const __attribute__((address_space(1))) unsigned int* as1_u32p;
typedef __attribute__((address_space(3))) unsigned int*       as3_u32p;

// async global->LDS, 16B per lane; LDS dest = wave-uniform base + lane*16 (linear)
__device__ __forceinline__ void gl_lds16(const void* g, void* l) {
  __builtin_amdgcn_global_load_lds(
      (as1_u32p)(reinterpret_cast<uintptr_t>(g)),
      (as3_u32p)((unsigned int)(reinterpret_cast<uintptr_t>(l))),
      16, 0, 0);
}

// XOR swizzle for tiles with 64-elem (128B) rows: 8 slots of 8 bf16; slot ^= row&7
__device__ __forceinline__ int swz64(int row, int col) {
  return row*64 + ((((col >> 3) ^ (row & 7)) << 3) | (col & 7));
}

__device__ __forceinline__ unsigned pkbf(float a, float b) {
  __hip_bfloat162 h = __float22bfloat162_rn(make_float2(a, b)); // x=lo, y=hi
  return *reinterpret_cast<unsigned*>(&h);
}

// permlane swaps (VALU pipe). Verified row semantics (involutions):
// perm16(d,s): d'=[d0,s0,d2,s2], s'=[d1,s1,d3,s3]   (16-lane rows)
// perm32(d,s): d'=[d0,d1,s0,s1], s'=[d2,d3,s2,s3]
__device__ __forceinline__ void perm16p(unsigned &a, unsigned &b) {
  asm("v_permlane16_swap_b32 %0, %1" : "+v"(a), "+v"(b));
}
__device__ __forceinline__ void perm32p(unsigned &a, unsigned &b) {
  asm("v_permlane32_swap_b32 %0, %1" : "+v"(a), "+v"(b));
}

// inline-asm LDS reads (opaque to alias analysis: no compiler-inserted vmcnt drains)
__device__ __forceinline__ short8 ldsr_o0(unsigned a) {
  short8 r; asm volatile("ds_read_b128 %0, %1" : "=v"(r) : "v"(a)); return r;
}
__device__ __forceinline__ short8 ldsr_o1(unsigned a) {
  short8 r; asm volatile("ds_read_b128 %0, %1 offset:2048" : "=v"(r) : "v"(a)); return r;
}
__device__ __forceinline__ short8 ldsr_o2(unsigned a) {
  short8 r; asm volatile("ds_read_b128 %0, %1 offset:4096" : "=v"(r) : "v"(a)); return r;
}
__device__ __forceinline__ short8 ldsr_o3(unsigned a) {
  short8 r; asm volatile("ds_read_b128 %0, %1 offset:6144" : "=v"(r) : "v"(a)); return r;
}
__device__ __forceinline__ short8 ldsr_o4(unsigned a) {
  short8 r; asm volatile("ds_read_b128 %0, %1 offset:8192" : "=v"(r) : "v"(a)); return r;
}
__device__ __forceinline__ short8 ldsr_o5(unsigned a) {
  short8 r; asm volatile("ds_read_b128 %0, %1 offset:10240" : "=v"(r) : "v"(a)); return r;
}

#define LGKM0  do { asm volatile("s_waitcnt lgkmcnt(0)"); __builtin_amdgcn_sched_barrier(0); } while(0)
#define VMCNT0 do { __builtin_amdgcn_sched_barrier(0); asm volatile("s_waitcnt vmcnt(0)"); __builtin_amdgcn_sched_barrier(0); } while(0)
#define BARRIER do { __builtin_amdgcn_s_barrier(); __builtin_amdgcn_sched_barrier(0); } while(0)

// ---------------- fp32 -> bf16 copy convert ----------------
__global__ __launch_bounds__(256) void k_cvt(const float* __restrict__ in,
                                             __hip_bfloat16* __restrict__ out, int n8) {
  int i = blockIdx.x * 256 + threadIdx.x;
  if (i >= n8) return;
  const float* p = in + (size_t)i * 8;
  short8 o;
#pragma unroll
  for (int j = 0; j < 8; ++j) {
    __hip_bfloat16 h = __float2bfloat16(p[j]);
    o[j] = *reinterpret_cast<short*>(&h);
  }
  *reinterpret_cast<short8*>(out + (size_t)i * 8) = o;
}

// ---------------- W [K][N] fp32 -> Wt [N][K] bf16 (tiled transpose) ----------------
__global__ __launch_bounds__(256) void k_transpose_cvt(const float* __restrict__ W,
                                                       __hip_bfloat16* __restrict__ Wt,
                                                       int K, int N) {
  __shared__ float tbuf[32][33];
  const int n0 = blockIdx.x * 32, k0 = blockIdx.y * 32;
  const int tx = threadIdx.x & 31, ty = threadIdx.x >> 5;
#pragma unroll
  for (int i = 0; i < 4; ++i)
    tbuf[ty + i*8][tx] = W[(size_t)(k0 + ty + i*8) * N + n0 + tx];
  __syncthreads();
#pragma unroll
  for (int i = 0; i < 4; ++i)
    Wt[(size_t)(n0 + ty + i*8) * K + k0 + tx] = __float2bfloat16(tbuf[tx][ty + i*8]);
}

// ---------------- 128x192 double-buffered QKV GEMM, 2 blocks/CU (r16-proven) ----------------
__global__ __launch_bounds__(512, 4) void k_gemm3(const __hip_bfloat16* __restrict__ A,
                                                  const __hip_bfloat16* __restrict__ Bt,
                                                  const float* __restrict__ bias,
                                                  __hip_bfloat16* __restrict__ Qb,
                                                  __hip_bfloat16* __restrict__ Kb,
                                                  __hip_bfloat16* __restrict__ Vtb) {
  __shared__ __hip_bfloat16 As[2][128 * 64];   // 16 KB per slot
  __shared__ __hip_bfloat16 Bs[2][192 * 64];   // 24 KB per slot
  const int tid = threadIdx.x;
  const int l = tid & 63, w = tid >> 6;
  const int lr = l & 15, lg = l >> 4;
  const int wm = w >> 2, wn = w & 3;           // 2m x 4n: 64 rows x 48 cols per wave
  const int m0 = blockIdx.x * 128, n0 = blockIdx.y * 192;

  const int srow = tid >> 3;                   // 0..63
  const int scol = (((tid & 7) ^ (srow & 7)) << 3);
  const size_t aoffs = (size_t)(m0 + srow) * 1024 + scol;
  const size_t boffs = (size_t)(n0 + srow) * 1024 + scol;
  const int ldst = tid * 8;

  auto stage = [&](int t, int s) {
    const int k0 = t * 64;
#pragma unroll
    for (int rd = 0; rd < 2; ++rd)
      gl_lds16(A + aoffs + (size_t)rd * 65536 + k0, &As[s][rd * 4096 + ldst]);
#pragma unroll
    for (int rd = 0; rd < 3; ++rd)
      gl_lds16(Bt + boffs + (size_t)rd * 65536 + k0, &Bs[s][rd * 4096 + ldst]);
  };

  const unsigned asLds = (unsigned)(uintptr_t)&As[0][0];
  const unsigned bsLds = (unsigned)(uintptr_t)&Bs[0][0];
  const unsigned aBase0 = asLds + 2u * ((wm*64 + lr) * 64 + ((lg ^ (lr & 7)) << 3));
  const unsigned bBase0 = bsLds + 2u * ((wn*48 + lr) * 64 + ((lg ^ (lr & 7)) << 3));

  stage(0, 0);
  VMCNT0;
  BARRIER;

  f32x4 acc[4][3] = {};
  short8 a_[4][2], b_[3][2];

#pragma unroll
  for (int t = 0; t < 16; ++t) {
    const int s = t & 1;
    const unsigned aB0 = aBase0 + (unsigned)s * 16384u;
    const unsigned aB1 = aB0 ^ 64u;
    const unsigned bB0 = bBase0 + (unsigned)s * 24576u;
    const unsigned bB1 = bB0 ^ 64u;
    if (t < 15) stage(t + 1, s ^ 1);
    a_[0][0] = ldsr_o0(aB0); a_[1][0] = ldsr_o1(aB0); a_[2][0] = ldsr_o2(aB0); a_[3][0] = ldsr_o3(aB0);
    a_[0][1] = ldsr_o0(aB1); a_[1][1] = ldsr_o1(aB1); a_[2][1] = ldsr_o2(aB1); a_[3][1] = ldsr_o3(aB1);
    b_[0][0] = ldsr_o0(bB0); b_[1][0] = ldsr_o1(bB0); b_[2][0] = ldsr_o2(bB0);
    b_[0][1] = ldsr_o0(bB1); b_[1][1] = ldsr_o1(bB1); b_[2][1] = ldsr_o2(bB1);
    LGKM0;
    __builtin_amdgcn_s_setprio(1);
#pragma unroll
    for (int m = 0; m < 4; ++m)
#pragma unroll
      for (int n = 0; n < 3; ++n)
#pragma unroll
        for (int ks = 0; ks < 2; ++ks)
          acc[m][n] = mfma16(a_[m][ks], b_[n][ks], acc[m][n]);
    __builtin_amdgcn_s_setprio(0);
    if (t < 15) { VMCNT0; }
    BARRIER;
  }

  __syncthreads();
  // ---- per-16-col-group LDS-bounce epilogue (3 groups/wave) ----
  __hip_bfloat16* reg = &Bs[0][0] + w * 3072;   // 8 waves x 3 groups x 1024 elems
  const int colbase = n0 + wn * 48;
  const int rowbase = m0 + wm * 64;
  const int bidx = rowbase >> 11;
  const int tbase = rowbase & 2047;
  const float qs = 0.18033688011112042f;   // 0.125 * log2(e) folded into Q
  float bv[3];
#pragma unroll
  for (int g = 0; g < 3; ++g) bv[g] = bias[colbase + g * 16 + lr];
#pragma unroll
  for (int g = 0; g < 3; ++g) {
    const int cg0 = colbase + g * 16;
    const int which = cg0 >> 10;
    __hip_bfloat16* rg = reg + g * 1024;
    if (which == 2) {
#pragma unroll
      for (int m = 0; m < 4; ++m)
#pragma unroll
        for (int r = 0; r < 4; ++r) {
          const int t = m * 16 + lg * 4 + r;
          rg[lr * 64 + (t ^ ((lr & 7) << 3))] = __float2bfloat16(acc[m][g][r] + bv[g]);
        }
    } else {
      const float sc = (which == 0) ? qs : 1.f;
#pragma unroll
      for (int m = 0; m < 4; ++m)
#pragma unroll
        for (int r = 0; r < 4; ++r) {
          const int t = m * 16 + lg * 4 + r;
          rg[t * 16 + (lr ^ (((t >> 2) & 1) << 3))] =
              __float2bfloat16((acc[m][g][r] + bv[g]) * sc);
        }
    }
  }
#pragma unroll
  for (int g = 0; g < 3; ++g) {
    const int cg0 = colbase + g * 16;
    const int which = cg0 >> 10;
    const int hh = (cg0 >> 6) & 15;
    const int dd0 = cg0 & 48;
    const size_t bh = (size_t)bidx * 16 + hh;
    const __hip_bfloat16* rg = reg + g * 1024;
    if (which < 2) {
      __hip_bfloat16* basep = (which == 0) ? Qb : Kb;
      const int t = l;
      const int Xc = ((t >> 2) & 1) << 3;
      short8 y0 = *reinterpret_cast<const short8*>(&rg[t * 16 + Xc]);
      short8 y1 = *reinterpret_cast<const short8*>(&rg[t * 16 + (Xc ^ 8)]);
      __hip_bfloat16* dst = basep + (bh * TT + tbase + t) * 64 + dd0;
      *reinterpret_cast<short8*>(dst) = y0;
      *reinterpret_cast<short8*>(dst + 8) = y1;
    } else {
      const int dd = l >> 2, tseg = l & 3;
      const int X = (dd & 7) << 3;
      const int S0 = (((tseg ^ (X >> 4)) & 3) << 4) | (X & 8);
      short8 y0 = *reinterpret_cast<const short8*>(&rg[dd * 64 + S0]);
      short8 y1 = *reinterpret_cast<const short8*>(&rg[dd * 64 + (S0 ^ 8)]);
      __hip_bfloat16* dst = Vtb + (bh * 64 + dd0 + dd) * TT + tbase + tseg * 16;
      *reinterpret_cast<short8*>(dst) = y0;
      *reinterpret_cast<short8*>(dst + 8) = y1;
    }
  }
}

// ---------------- 128x128 double-buffered dist-1 GEMM (proj), 2 blocks/CU ----------------
__global__ __launch_bounds__(256, 2) void k_gemm2(const __hip_bfloat16* __restrict__ A,
                                                  const __hip_bfloat16* __restrict__ Bt,
                                                  const float* __restrict__ bias,
                                                  float* __restrict__ outF) {
  __shared__ __hip_bfloat16 As[2][128 * 64];
  __shared__ __hip_bfloat16 Bs[2][128 * 64];
  const int tid = threadIdx.x;
  const int l = tid & 63, w = tid >> 6;
  const int lr = l & 15, lg = l >> 4;
  const int wm = w >> 1, wn = w & 1;
  const int m0 = blockIdx.x * 128, n0 = blockIdx.y * 128;

  const int srow = tid >> 3;                 // 0..31
  const int scol = (((tid & 7) ^ (srow & 7)) << 3);
  const size_t aoffs = (size_t)(m0 + srow) * 1024 + scol;
  const size_t boffs = (size_t)(n0 + srow) * 1024 + scol;
  const int ldst = tid * 8;

  auto stage = [&](int t, int s) {
    const int k0 = t * 64;
#pragma unroll
    for (int rd = 0; rd < 4; ++rd) {
      gl_lds16(A + aoffs + (size_t)rd * 32768 + k0, &As[s][rd * 2048 + ldst]);
      gl_lds16(Bt + boffs + (size_t)rd * 32768 + k0, &Bs[s][rd * 2048 + ldst]);
    }
  };

  const unsigned asLds = (unsigned)(uintptr_t)&As[0][0];
  const unsigned bsLds = (unsigned)(uintptr_t)&Bs[0][0];
  const unsigned aBase0 = asLds + 2u * ((wm*64 + lr) * 64 + ((lg ^ (lr & 7)) << 3));
  const unsigned bBase0 = bsLds + 2u * ((wn*64 + lr) * 64 + ((lg ^ (lr & 7)) << 3));

  stage(0, 0);
  VMCNT0;
  BARRIER;

  f32x4 acc[4][4] = {};
  short8 a_[4][2], b_[4][2];

#pragma unroll
  for (int t = 0; t < 16; ++t) {
    const int s = t & 1;
    const unsigned aB0 = aBase0 + (unsigned)s * 16384u;
    const unsigned aB1 = aB0 ^ 64u;
    const unsigned bB0 = bBase0 + (unsigned)s * 16384u;
    const unsigned bB1 = bB0 ^ 64u;
    if (t < 15) stage(t + 1, s ^ 1);
    a_[0][0] = ldsr_o0(aB0); a_[1][0] = ldsr_o1(aB0); a_[2][0] = ldsr_o2(aB0); a_[3][0] = ldsr_o3(aB0);
    a_[0][1] = ldsr_o0(aB1); a_[1][1] = ldsr_o1(aB1); a_[2][1] = ldsr_o2(aB1); a_[3][1] = ldsr_o3(aB1);
    b_[0][0] = ldsr_o0(bB0); b_[1][0] = ldsr_o1(bB0); b_[2][0] = ldsr_o2(bB0); b_[3][0] = ldsr_o3(bB0);
    b_[0][1] = ldsr_o0(bB1); b_[1][1] = ldsr_o1(bB1); b_[2][1] = ldsr_o2(bB1); b_[3][1] = ldsr_o3(bB1);
    LGKM0;
    __builtin_amdgcn_s_setprio(1);
#pragma unroll
    for (int m = 0; m < 4; ++m)
#pragma unroll
      for (int n = 0; n < 4; ++n)
#pragma unroll
        for (int ks = 0; ks < 2; ++ks)
          acc[m][n] = mfma16(a_[m][ks], b_[n][ks], acc[m][n]);
    __builtin_amdgcn_s_setprio(0);
    if (t < 15) { VMCNT0; }
    BARRIER;
  }

  __syncthreads();
#pragma unroll
  for (int n = 0; n < 4; ++n) {
    const int col = n0 + wn * 64 + n * 16 + lr;
    const float bvv = bias[col];
#pragma unroll
    for (int m = 0; m < 4; ++m)
#pragma unroll
      for (int r = 0; r < 4; ++r) {
        const int row = m0 + wm * 64 + m * 16 + lg * 4 + r;
        outF[(size_t)row * 1024 + col] = acc[m][n][r] + bvv;
      }
  }
}

// ---------------- causal flash attention (merged paired q-tiles, mfma-lrun; r17-proven) ----------------
// Fixed-max softmax, sigma-permuted K rows -> P redistribution = 2x permlane16_swap +
// 2x permlane32_swap; row-sum l on the MFMA pipe via all-ones A-fragment.
__device__ __forceinline__ void tile_step(f32x4 s0, f32x4 s1, int kbase, int kmaxw, int qmb,
                                          short8 ones,
                                          short8 v0, short8 v1, short8 v2, short8 v3,
                                          f32x4 (&acc)[4], f32x4& accL) {
  if (kbase + 31 > kmaxw - 15) {       // diagonal chunk: per-element causal mask
#pragma unroll
    for (int r = 0; r < 4; ++r) {
      const int off = (r & 1) + ((r & 2) << 2);   // 0,1,8,9
      if (kbase + off > qmb)      s0[r] = -INFINITY;
      if (kbase + 16 + off > qmb) s1[r] = -INFINITY;
    }
  }
  float p0 = __builtin_amdgcn_exp2f(s0[0]), p1 = __builtin_amdgcn_exp2f(s0[1]);
  float p2 = __builtin_amdgcn_exp2f(s0[2]), p3 = __builtin_amdgcn_exp2f(s0[3]);
  float p4 = __builtin_amdgcn_exp2f(s1[0]), p5 = __builtin_amdgcn_exp2f(s1[1]);
  float p6 = __builtin_amdgcn_exp2f(s1[2]), p7 = __builtin_amdgcn_exp2f(s1[3]);
  unsigned u0 = pkbf(p0, p1);
  unsigned u1 = pkbf(p2, p3);
  unsigned u2 = pkbf(p4, p5);
  unsigned u3 = pkbf(p6, p7);
  perm16p(u0, u1);
  perm16p(u2, u3);
  perm32p(u0, u2);
  perm32p(u1, u3);
  union { unsigned u[4]; short8 s; } pw;
  pw.u[0] = u0; pw.u[1] = u2; pw.u[2] = u1; pw.u[3] = u3;
  const short8 pf = pw.s;
  acc[0] = mfma16(v0, pf, acc[0]);
  acc[1] = mfma16(v1, pf, acc[1]);
  acc[2] = mfma16(v2, pf, acc[2]);
  acc[3] = mfma16(v3, pf, acc[3]);
  accL   = mfma16(ones, pf, accL);   // row-sum of P on the MFMA pipe
}

__device__ __forceinline__ void store_tile(__hip_bfloat16* Ylds, f32x4 (&acc)[4],
                                           float lsum, int q0, int w, int l,
                                           int lr, int lg, int bh,
                                           __hip_bfloat16* __restrict__ Y) {
  const float inv = 1.f / lsum;      // accL[0]: every lane holds full sum for q=lane&15
#pragma unroll
  for (int nb = 0; nb < 4; ++nb) {
#pragma unroll
    for (int r = 0; r < 4; ++r) {
      const int d = nb * 16 + lg * 4 + r;
      Ylds[swz64(lr, d)] = __float2bfloat16(acc[nb][r] * inv);
    }
  }
  const int rr = l >> 2, part = l & 3;
  const int trow = q0 + w * 16 + rr;
  const int b = bh >> 4, h = bh & 15;
  short8 y0 = *reinterpret_cast<const short8*>(&Ylds[swz64(rr, part * 16)]);
  short8 y1 = *reinterpret_cast<const short8*>(&Ylds[swz64(rr, part * 16 + 8)]);
  __hip_bfloat16* dst = Y + ((size_t)b * TT + trow) * 1024 + h * 64 + part * 16;
  *reinterpret_cast<short8*>(dst) = y0;
  *reinterpret_cast<short8*>(dst + 8) = y1;
}

__global__ __launch_bounds__(256, 4) void k_flash(const __hip_bfloat16* __restrict__ Qb,
                                                  const __hip_bfloat16* __restrict__ Kb,
                                                  const __hip_bfloat16* __restrict__ Vtb,
                                                  __hip_bfloat16* __restrict__ Y) {
  __shared__ __hip_bfloat16 Klds[128 * 64];
  __shared__ __hip_bfloat16 Vtlds[64 * 128];
  const int tid = threadIdx.x;
  const int l = tid & 63, w = tid >> 6;
  const int lr = l & 15, lg = l >> 4;
  const int p  = blockIdx.x >> 6;       // pair index 0..15
  const int bh = blockIdx.x & 63;
  const int q0A = p * 64, q0B = (31 - p) * 64;
  const __hip_bfloat16* Qp = Qb + (size_t)bh * TT * 64;
  const __hip_bfloat16* Kp = Kb + (size_t)bh * TT * 64;
  const __hip_bfloat16* Vp = Vtb + (size_t)bh * 64 * TT;
  const int qrowA = q0A + w * 16 + lr;
  const int qrowB = q0B + w * 16 + lr;
  const short8 qfA0 = *reinterpret_cast<const short8*>(Qp + (size_t)qrowA * 64 + lg * 8);
  const short8 qfA1 = *reinterpret_cast<const short8*>(Qp + (size_t)qrowA * 64 + 32 + lg * 8);
  const short8 qfB0 = *reinterpret_cast<const short8*>(Qp + (size_t)qrowB * 64 + lg * 8);
  const short8 qfB1 = *reinterpret_cast<const short8*>(Qp + (size_t)qrowB * 64 + 32 + lg * 8);
  f32x4 accA[4] = {}, accB[4] = {};
  f32x4 accLA = {}, accLB = {};
  union { unsigned u[4]; short8 s; } onesu;
  onesu.u[0] = onesu.u[1] = onesu.u[2] = onesu.u[3] = 0x3F803F80u;  // bf16 1.0 pairs
  const short8 ones = onesu.s;

  const int ka  = lr * 64 + ((lg ^ (lr & 7)) << 3);
  const int va  = lr * 128 + ((lg ^ (lr & 15)) << 3);

  const __hip_bfloat16* gk[4];
  const __hip_bfloat16* gv[4];
  __hip_bfloat16* lk[4];
  __hip_bfloat16* lv[4];
#pragma unroll
  for (int it = 0; it < 4; ++it) {
    int e = it * 2048 + tid * 8;
    int rowk = e >> 6;
    int lcolk = ((((e >> 3) & 7) ^ (rowk & 7)) << 3);
    int rk = rowk & 15;
    int srk = (((rk >> 1) ^ (rk >> 3)) & 1) ? (rk ^ 10) : rk;
    int rowks = (rowk & ~15) | srk;
    gk[it] = Kp + (size_t)rowks * 64 + lcolk;
    lk[it] = &Klds[e];
    int rowv = e >> 7;
    int lcolv = ((((e >> 3) & 15) ^ (rowv & 15)) << 3);
    gv[it] = Vp + (size_t)rowv * TT + lcolv;
    lv[it] = &Vtlds[e];
  }

  const int kmaxwA = q0A + w * 16 + 15;
  const int kmaxwB = q0B + w * 16 + 15;
  const int base_lg = ((lg & 1) << 2) | (lg & 2);
  const int qmbA = qrowA - base_lg;
  const int qmbB = qrowB - base_lg;
  const int nblk = (q0B + 63) / 128 + 1;
  for (int blk = 0; blk < nblk; ++blk) {
    const int kv0 = blk * 128;
#pragma unroll
    for (int it = 0; it < 4; ++it) {
      gl_lds16(gk[it], lk[it]);
      gk[it] += 128 * 64;
    }
#pragma unroll
    for (int it = 0; it < 4; ++it) {
      gl_lds16(gv[it], lv[it]);
      gv[it] += 128;
    }
    __syncthreads();
#pragma unroll
    for (int kci = 0; kci < 4; ++kci) {
      const int kbase = kv0 + kci * 32;
      if (kbase > kmaxwB) break;
      const int kb = ka + kci * 2048;
      const short8 kf00 = *reinterpret_cast<const short8*>(&Klds[kb]);
      const short8 kf10 = *reinterpret_cast<const short8*>(&Klds[kb + 1024]);
      const short8 kf01 = *reinterpret_cast<const short8*>(&Klds[kb ^ 32]);
      const short8 kf11 = *reinterpret_cast<const short8*>(&Klds[(kb + 1024) ^ 32]);
      f32x4 sB0 = {}, sB1 = {};
      sB0 = mfma16(kf00, qfB0, sB0);
      sB1 = mfma16(kf10, qfB0, sB1);
      sB0 = mfma16(kf01, qfB1, sB0);
      sB1 = mfma16(kf11, qfB1, sB1);
      const bool aAct = (kbase <= kmaxwA);
      f32x4 sA0 = {}, sA1 = {};
      if (aAct) {
        sA0 = mfma16(kf00, qfA0, sA0);
        sA1 = mfma16(kf10, qfA0, sA1);
        sA0 = mfma16(kf01, qfA1, sA0);
        sA1 = mfma16(kf11, qfA1, sA1);
      }
      const int vb = va ^ (kci * 32);
      const short8 v0 = *reinterpret_cast<const short8*>(&Vtlds[vb]);
      const short8 v1 = *reinterpret_cast<const short8*>(&Vtlds[vb + 2048]);
      const short8 v2 = *reinterpret_cast<const short8*>(&Vtlds[vb + 4096]);
      const short8 v3 = *reinterpret_cast<const short8*>(&Vtlds[vb + 6144]);
      tile_step(sB0, sB1, kbase, kmaxwB, qmbB, ones, v0, v1, v2, v3, accB, accLB);
      if (aAct)
        tile_step(sA0, sA1, kbase, kmaxwA, qmbA, ones, v0, v1, v2, v3, accA, accLA);
    }
    __syncthreads();
  }
  __hip_bfloat16* Ylds = Klds + w * 1024;
  store_tile(Ylds, accA, accLA[0], q0A, w, l, lr, lg, bh, Y);
  store_tile(Ylds, accB, accLB[0], q0B, w, l, lr, lg, bh, Y);
}

// ---------------- launch ----------------
extern "C" void kernel_launch(void* const* d_in, const int* in_sizes, int n_in,
                              void* d_out, int out_size, void* d_ws, size_t ws_size,
                              hipStream_t stream) {
  const float* x     = (const float*)d_in[0];
  const float* Wqkv  = (const float*)d_in[1];
  const float* bqkv  = (const float*)d_in[2];
  const float* Wproj = (const float*)d_in[3];
  const float* bproj = (const float*)d_in[4];

  char* ws = (char*)d_ws;
  size_t off = 0;
  auto alloc = [&](size_t bytes) {
    char* p = ws + off;
    off += (bytes + 255) & ~(size_t)255;
    return p;
  };
  __hip_bfloat16* xb    = (__hip_bfloat16*)alloc((size_t)MTOT * 1024 * 2);
  __hip_bfloat16* wqkvT = (__hip_bfloat16*)alloc((size_t)3072 * 1024 * 2);
  __hip_bfloat16* wpT   = (__hip_bfloat16*)alloc((size_t)1024 * 1024 * 2);
  __hip_bfloat16* Qb    = (__hip_bfloat16*)alloc((size_t)64 * TT * 64 * 2);
  __hip_bfloat16* Kb    = (__hip_bfloat16*)alloc((size_t)64 * TT * 64 * 2);
  __hip_bfloat16* Vtb   = (__hip_bfloat16*)alloc((size_t)64 * TT * 64 * 2);
  __hip_bfloat16* Yb    = (__hip_bfloat16*)alloc((size_t)MTOT * 1024 * 2);

  k_cvt<<<(MTOT * 1024 / 8 + 255) / 256, 256, 0, stream>>>(x, xb, MTOT * 1024 / 8);
  k_transpose_cvt<<<dim3(3072 / 32, 1024 / 32), 256, 0, stream>>>(Wqkv, wqkvT, 1024, 3072);
  k_transpose_cvt<<<dim3(1024 / 32, 1024 / 32), 256, 0, stream>>>(Wproj, wpT, 1024, 1024);
  k_gemm3<<<dim3(64, 16), 512, 0, stream>>>(xb, wqkvT, bqkv, Qb, Kb, Vtb);
  k_flash<<<16 * 64, 256, 0, stream>>>(Qb, Kb, Vtb, Yb);
  k_gemm2<<<dim3(64, 8), 256, 0, stream>>>(Yb, wpT, bproj, (float*)d_out);
}